// Round 4
// baseline (152.643 us; speedup 1.0000x reference)
//
#include <hip/hip_runtime.h>

typedef __attribute__((ext_vector_type(2))) _Float16 h2;
typedef __attribute__((ext_vector_type(2))) __fp16 p2;   // cvt_pkrtz return type
typedef __attribute__((ext_vector_type(8))) _Float16 f16x8;
typedef __attribute__((ext_vector_type(4))) float fv4;
typedef __attribute__((ext_vector_type(4))) int iv4;
typedef unsigned int u32;

#define K_IN 4096
#define N_OUT 4096

// ---------------------------------------------------------------------------
// Kernel 1: xa[b][r] = sum_i x[b][i] * lora_a[r][i]
// ---------------------------------------------------------------------------
__global__ __launch_bounds__(256) void xa_kernel(const float* __restrict__ x,
                                                 const float* __restrict__ la,
                                                 float* __restrict__ xa) {
    int t = threadIdx.x;
    int bl = t >> 6;          // wave id = local b row
    int r = (t >> 2) & 15;
    int ks = t & 3;
    int b = blockIdx.x * 4 + bl;
    const fv4* xp = (const fv4*)(x + (size_t)b * K_IN + ks * 1024);
    const fv4* ap = (const fv4*)(la + (size_t)r * K_IN + ks * 1024);
    float acc = 0.f;
#pragma unroll 8
    for (int i = 0; i < 256; ++i) {
        fv4 xv = xp[i], av = ap[i];
        acc += xv.x * av.x + xv.y * av.y + xv.z * av.z + xv.w * av.w;
    }
    acc += __shfl_xor(acc, 1);
    acc += __shfl_xor(acc, 2);
    if (ks == 0) xa[b * 16 + r] = acc;
}

// ---------------------------------------------------------------------------
// Kernel 2: fused dequant GEMM + rank-16 LoRA.
// 512 blocks x 256 thr (4 waves). BM=128, BN=64, BK=64, 64 K-steps.
// Wave grid (wm,kg)=2x2: wave tile 64x64 over one k32 half of each K-step.
// LDS 80KB -> 2 blocks/CU:
//   A: fp32 dbuf [128 rows][256B] @0/32768, filled by global_load_lds with
//      pre-swizzled per-lane SOURCE addresses (dest linear, layout = g^(row&15)).
//   B: f16 dbuf [64 cols][128B] @65536/73728, reg-staged dequant, g^(col&7).
// ---------------------------------------------------------------------------
__global__ __launch_bounds__(256, 2) void qlora_gemm(
        const float* __restrict__ x, const int* __restrict__ qw,
        const float* __restrict__ sc, const float* __restrict__ lb,
        const float* __restrict__ alphap, const float* __restrict__ xa,
        float* __restrict__ out)
{
    __shared__ __align__(16) char lds[81920];

    // XCD q = bid&7 owns one by (A panel L2-resident per XCD).
    int bid = blockIdx.x;
    int by = bid & 7, bx = bid >> 3;   // 8 x 64 tiles
    int bm0 = by << 7, bn0 = bx << 6;

    int t = threadIdx.x;
    int lane = t & 63;
    int wid = t >> 6;                  // 0..3
    int kg = wid & 1, wm = wid >> 1;
    int rl = lane & 15, hq = lane >> 4;

    // ---- A-DMA per-lane swizzled source bases (instr i uses base[i&3]) ----
    const char* xb = (const char*)x;
    const char* abase[4];
#pragma unroll
    for (int j = 0; j < 4; ++j) {
        int row = wid * 32 + 4 * j + hq;            // local row for chunk i=j
        int g = rl ^ ((4 * j) | hq);                // source granule for this lane
        abase[j] = xb + (size_t)(bm0 + row) * (K_IN * 4) + g * 16;
    }

    auto DMA_A = [&](int ts, int buf) {
        char* dst0 = lds + buf * 32768 + wid * 8192;
#pragma unroll
        for (int i = 0; i < 8; ++i) {
            const char* src = abase[i & 3] + (i >> 2) * 262144 + ts * 256;
            __builtin_amdgcn_global_load_lds(
                (const __attribute__((address_space(1))) u32*)src,
                (__attribute__((address_space(3))) u32*)(dst0 + i * 1024),
                16, 0, 0);
        }
    };

    // ---- B staging: thread -> (colL = t>>2, group q4 = t&3) ----
    int colL = t >> 2, q4 = t & 3;
    const int* qwp = qw + ((size_t)(bn0 + colL) * 256 + q4) * 8;
    const float* scp = sc + (size_t)(bn0 + colL) * 256 + q4;

    iv4 Bq0, Bq1;
    float Bsc;
    auto LOADB = [&](int ts) {
        Bq0 = *(const iv4*)(qwp + (size_t)ts * 32);
        Bq1 = *(const iv4*)(qwp + (size_t)ts * 32 + 4);
        Bsc = scp[(size_t)ts * 4];
    };

    auto STOREB = [&](int buf) {
        char* Bb = lds + 65536 + buf * 8192;
        float s = Bsc;
        _Float16 c0h = (_Float16)(s * (2.0f / 15.0f));
        _Float16 c1h = (_Float16)(-s);
        h2 c0 = {c0h, c0h}, c1 = {c1h, c1h};
        h2 m1024 = {(_Float16)-1024.f, (_Float16)-1024.f};
        union { h2 h[4]; iv4 v; } o0, o1;
        int vals[8] = {Bq0.x, Bq0.y, Bq0.z, Bq0.w, Bq1.x, Bq1.y, Bq1.z, Bq1.w};
#pragma unroll
        for (int e = 0; e < 8; ++e) {
            unsigned wv = (unsigned)vals[e];
            unsigned qb = (wv & 15u) | ((wv & 0xF0u) << 12) | 0x64006400u;
            h2 qh;
            __builtin_memcpy(&qh, &qb, 4);
            h2 r = (qh + m1024) * c0 + c1;
            if (e < 4) o0.h[e] = r; else o1.h[e - 4] = r;
        }
        int g0w = (q4 * 2) ^ (colL & 7);
        int g1w = (q4 * 2 + 1) ^ (colL & 7);
        *(iv4*)(Bb + colL * 128 + (g0w << 4)) = o0.v;
        *(iv4*)(Bb + colL * 128 + (g1w << 4)) = o1.v;
    };

    fv4 acc[4][4];
#pragma unroll
    for (int m = 0; m < 4; ++m)
#pragma unroll
        for (int n = 0; n < 4; ++n)
            acc[m][n] = fv4{0.f, 0.f, 0.f, 0.f};

    // ---- COMPUTE: one k32 slice (this wave's kg half) of current K-step ----
    auto COMPUTE = [&](const char* As, const char* Bb, int g0, int h0) {
        f16x8 a[4], b[4];
#pragma unroll
        for (int m = 0; m < 4; ++m) {
            int row = wm * 64 + m * 16 + rl;      // row & 15 == rl
            fv4 vlo = *(const fv4*)(As + row * 256 + ((g0 ^ rl) << 4));
            fv4 vhi = *(const fv4*)(As + row * 256 + (((g0 + 1) ^ rl) << 4));
            union { p2 h[4]; f16x8 v; } ua;
            ua.h[0] = __builtin_amdgcn_cvt_pkrtz(vlo.x, vlo.y);
            ua.h[1] = __builtin_amdgcn_cvt_pkrtz(vlo.z, vlo.w);
            ua.h[2] = __builtin_amdgcn_cvt_pkrtz(vhi.x, vhi.y);
            ua.h[3] = __builtin_amdgcn_cvt_pkrtz(vhi.z, vhi.w);
            a[m] = ua.v;
        }
#pragma unroll
        for (int n = 0; n < 4; ++n) {
            int col = n * 16 + rl;
            b[n] = *(const f16x8*)(Bb + col * 128 + ((h0 ^ (col & 7)) << 4));
        }
#pragma unroll
        for (int m = 0; m < 4; ++m)
#pragma unroll
            for (int n = 0; n < 4; ++n)
                acc[m][n] = __builtin_amdgcn_mfma_f32_16x16x32_f16(
                    a[m], b[n], acc[m][n], 0, 0, 0);
    };

    // ---- main loop: 2-phase dbuf, DMA-A + reg-staged B, one barrier/step ----
    LOADB(0);
    DMA_A(0, 0);
    STOREB(0);
    __syncthreads();
#pragma unroll 2
    for (int ts = 0; ts < 64; ++ts) {
        int buf = ts & 1;
        if (ts < 63) { LOADB(ts + 1); DMA_A(ts + 1, buf ^ 1); }
        COMPUTE(lds + buf * 32768, lds + 65536 + buf * 8192,
                kg * 8 + hq * 2, kg * 4 + hq);
        if (ts < 63) STOREB(buf ^ 1);
        __syncthreads();
    }

    // ---- LoRA rank-16 extra K-step (k 0..15 data, 16..31 zeros) ----
    {
        int lrow = t >> 1, halfg = t & 1;
        const float* xr = xa + (size_t)(bm0 + lrow) * 16;
#pragma unroll
        for (int j = 0; j < 4; ++j) {
            int g = halfg * 4 + j;
            fv4 v = (halfg == 0) ? *(const fv4*)(xr + g * 4) : fv4{0.f, 0.f, 0.f, 0.f};
            *(fv4*)(lds + lrow * 256 + ((g ^ (lrow & 15)) << 4)) = v;
        }
        float al = alphap[0];
        int colE = t >> 2, ge = t & 3;
        union { p2 h[4]; iv4 v; } ob;
        if (ge < 2) {
            const float* wp = lb + (size_t)(bn0 + colE) * 16 + ge * 8;
#pragma unroll
            for (int e2 = 0; e2 < 4; ++e2)
                ob.h[e2] = __builtin_amdgcn_cvt_pkrtz(al * wp[2 * e2], al * wp[2 * e2 + 1]);
        } else {
            ob.v = iv4{0, 0, 0, 0};
        }
        *(iv4*)(lds + 65536 + colE * 128 + ((ge ^ (colE & 7)) << 4)) = ob.v;
    }
    __syncthreads();

    if (kg == 0) {
        COMPUTE(lds, lds + 65536, hq * 2, hq);
    } else {
        // kg==1: dump partials for the kg==0 partner (same wm).
        char* dmp = lds + 32768 + wm * 16384;
#pragma unroll
        for (int m = 0; m < 4; ++m)
#pragma unroll
            for (int n = 0; n < 4; ++n)
                *(fv4*)(dmp + (m * 4 + n) * 1024 + lane * 16) = acc[m][n];
    }
    __syncthreads();

    if (kg == 0) {
        const char* dmp = lds + 32768 + wm * 16384;
#pragma unroll
        for (int m = 0; m < 4; ++m) {
            int row0 = bm0 + wm * 64 + m * 16 + hq * 4;
#pragma unroll
            for (int n = 0; n < 4; ++n) {
                fv4 p = *(const fv4*)(dmp + (m * 4 + n) * 1024 + lane * 16);
                fv4 v = acc[m][n];
                v.x += p.x; v.y += p.y; v.z += p.z; v.w += p.w;
                int col = bn0 + n * 16 + rl;
#pragma unroll
                for (int r = 0; r < 4; ++r)
                    out[(size_t)(row0 + r) * N_OUT + col] = v[r];
            }
        }
    }
}

extern "C" void kernel_launch(void* const* d_in, const int* in_sizes, int n_in,
                              void* d_out, int out_size, void* d_ws, size_t ws_size,
                              hipStream_t stream) {
    const float* x  = (const float*)d_in[0];
    const int*   qw = (const int*)d_in[1];
    const float* sc = (const float*)d_in[2];
    const float* la = (const float*)d_in[3];
    const float* lb = (const float*)d_in[4];
    const float* al = (const float*)d_in[5];
    float* out = (float*)d_out;
    float* xa  = (float*)d_ws;   // 1024*16 fp32 = 64 KB scratch

    xa_kernel<<<256, 256, 0, stream>>>(x, la, xa);
    qlora_gemm<<<512, 256, 0, stream>>>(x, qw, sc, lb, al, xa, out);
}

// Round 5
// 135.037 us; speedup vs baseline: 1.1304x; 1.1304x over previous
//
#include <hip/hip_runtime.h>

typedef __attribute__((ext_vector_type(2))) _Float16 h2;
typedef __attribute__((ext_vector_type(2))) __fp16 p2;   // cvt_pkrtz return type
typedef __attribute__((ext_vector_type(8))) _Float16 f16x8;
typedef __attribute__((ext_vector_type(4))) float fv4;
typedef __attribute__((ext_vector_type(4))) int iv4;

#define K_IN 4096
#define N_OUT 4096

// ---------------------------------------------------------------------------
// Kernel 1: xa[b][r] = sum_i x[b][i] * lora_a[r][i]
// 1024 blocks x 256 thr; tid -> (p = b*16+r) = tid>>4, ks = tid&15.
// Per thread: 256 f32 (64 fv4, unroll 8); reduce over 16 ks lanes.
// x addrs broadcast across the 16 r's of a wave -> L1-served.
// ---------------------------------------------------------------------------
__global__ __launch_bounds__(256) void xa_kernel(const float* __restrict__ x,
                                                 const float* __restrict__ la,
                                                 float* __restrict__ xa) {
    int tid = blockIdx.x * 256 + threadIdx.x;
    int ks = tid & 15;
    int p = tid >> 4;           // 0..16383 = b*16 + r
    int b = p >> 4, r = p & 15;
    const fv4* xp = (const fv4*)(x + (size_t)b * K_IN + ks * 256);
    const fv4* ap = (const fv4*)(la + (size_t)r * K_IN + ks * 256);
    float acc = 0.f;
#pragma unroll 8
    for (int i = 0; i < 64; ++i) {
        fv4 xv = xp[i], av = ap[i];
        acc += xv.x * av.x + xv.y * av.y + xv.z * av.z + xv.w * av.w;
    }
    acc += __shfl_xor(acc, 1);
    acc += __shfl_xor(acc, 2);
    acc += __shfl_xor(acc, 4);
    acc += __shfl_xor(acc, 8);
    if (ks == 0) xa[p] = acc;
}

// ---------------------------------------------------------------------------
// Kernel 2: fused dequant GEMM + rank-16 LoRA.
// 512 blocks x 256 thr (4 waves). BM=128, BN=64, BK=64, 64 K-steps.
// Wave grid (wm,kg)=2x2: wave tile 64x64 over one k32 half of each K-step.
// LDS 80KB -> 2 blocks/CU:
//   A f16 dbuf [128 rows][128B] @0/16384   (granule XOR swizzle g^(row&7))
//   B f16 dbuf [64 cols][128B] @32768/40960 (g^(col&7))
//   partial-acc dump @49152 + wm*16384
// Pipeline: LOAD(t+1) -> COMPUTE(t) [setprio around MFMA] -> STORE(t+1) -> bar.
// ---------------------------------------------------------------------------
__global__ __launch_bounds__(256, 2) void qlora_gemm(
        const float* __restrict__ x, const int* __restrict__ qw,
        const float* __restrict__ sc, const float* __restrict__ lb,
        const float* __restrict__ alphap, const float* __restrict__ xa,
        float* __restrict__ out)
{
    __shared__ __align__(16) char lds[81920];

    // XCD q = bid&7 owns one by (A panel shared within XCD).
    int bid = blockIdx.x;
    int by = bid & 7, bx = bid >> 3;   // 8 x 64 tiles
    int bm0 = by << 7, bn0 = bx << 6;

    int t = threadIdx.x;
    int lane = t & 63;
    int wid = t >> 6;                  // 0..3
    int kg = wid & 1, wm = wid >> 1;
    int rl = lane & 15, hq = lane >> 4;
    int r7 = rl & 7;

    // ---- A staging slots: inst i covers row = i*32 + (t>>3), granule t&7 ----
    int arow = t >> 3;                 // 0..31 (+i*32)
    int ag = t & 7;
    const float* agp = x + (size_t)(bm0 + arow) * K_IN + ag * 8;

    // ---- B staging: thread -> (colB = t>>2, q4 = t&3) ----
    int colB = t >> 2, q4 = t & 3;
    const int* qwp = qw + ((size_t)(bn0 + colB) * 256 + q4) * 8;
    const float* scp = sc + (size_t)(bn0 + colB) * 256 + q4;

    fv4 Ar[8];
    iv4 Bq0, Bq1;
    float Bsc;

    auto LOAD = [&](int ts) {
#pragma unroll
        for (int i = 0; i < 4; ++i) {
            const float* p = agp + (size_t)i * 32 * K_IN + ts * 64;
            Ar[2 * i] = *(const fv4*)(p);
            Ar[2 * i + 1] = *(const fv4*)(p + 4);
        }
        Bq0 = *(const iv4*)(qwp + (size_t)ts * 32);
        Bq1 = *(const iv4*)(qwp + (size_t)ts * 32 + 4);
        Bsc = scp[(size_t)ts * 4];
    };

    auto STORE = [&](int buf) {
        char* As = lds + buf * 16384;
        char* Bs = lds + 32768 + buf * 8192;
#pragma unroll
        for (int i = 0; i < 4; ++i) {
            int row = i * 32 + arow;
            union { p2 h[4]; iv4 v; } u;
            u.h[0] = __builtin_amdgcn_cvt_pkrtz(Ar[2 * i].x, Ar[2 * i].y);
            u.h[1] = __builtin_amdgcn_cvt_pkrtz(Ar[2 * i].z, Ar[2 * i].w);
            u.h[2] = __builtin_amdgcn_cvt_pkrtz(Ar[2 * i + 1].x, Ar[2 * i + 1].y);
            u.h[3] = __builtin_amdgcn_cvt_pkrtz(Ar[2 * i + 1].z, Ar[2 * i + 1].w);
            *(iv4*)(As + row * 128 + ((ag ^ (row & 7)) << 4)) = u.v;
        }
        // B dequant: 16 weights (2 groups) via f16-bias trick
        float s = Bsc;
        _Float16 c0h = (_Float16)(s * (2.0f / 15.0f));
        _Float16 c1h = (_Float16)(-s);
        h2 c0 = {c0h, c0h}, c1 = {c1h, c1h};
        h2 m1024 = {(_Float16)-1024.f, (_Float16)-1024.f};
        union { h2 h[4]; iv4 v; } o0, o1;
        int vals[8] = {Bq0.x, Bq0.y, Bq0.z, Bq0.w, Bq1.x, Bq1.y, Bq1.z, Bq1.w};
#pragma unroll
        for (int e = 0; e < 8; ++e) {
            unsigned wv = (unsigned)vals[e];
            unsigned qb = (wv & 15u) | ((wv & 0xF0u) << 12) | 0x64006400u;
            h2 qh;
            __builtin_memcpy(&qh, &qb, 4);
            h2 r = (qh + m1024) * c0 + c1;
            if (e < 4) o0.h[e] = r; else o1.h[e - 4] = r;
        }
        int c7 = colB & 7;
        *(iv4*)(Bs + colB * 128 + (((2 * q4) ^ c7) << 4)) = o0.v;
        *(iv4*)(Bs + colB * 128 + (((2 * q4 + 1) ^ c7) << 4)) = o1.v;
    };

    fv4 acc[4][4];
#pragma unroll
    for (int m = 0; m < 4; ++m)
#pragma unroll
        for (int n = 0; n < 4; ++n)
            acc[m][n] = fv4{0.f, 0.f, 0.f, 0.f};

    auto COMPUTE = [&](int buf, int kgg) {
        const char* As = lds + buf * 16384;
        const char* Bs = lds + 32768 + buf * 8192;
        f16x8 a[4], b[4];
        int gk = kgg * 4 + hq;
        int gs = (gk ^ r7) << 4;
#pragma unroll
        for (int m = 0; m < 4; ++m) {
            int row = wm * 64 + m * 16 + rl;
            a[m] = *(const f16x8*)(As + row * 128 + gs);
        }
#pragma unroll
        for (int n = 0; n < 4; ++n) {
            int col = n * 16 + rl;
            b[n] = *(const f16x8*)(Bs + col * 128 + gs);
        }
        __builtin_amdgcn_s_setprio(1);
#pragma unroll
        for (int m = 0; m < 4; ++m)
#pragma unroll
            for (int n = 0; n < 4; ++n)
                acc[m][n] = __builtin_amdgcn_mfma_f32_16x16x32_f16(
                    a[m], b[n], acc[m][n], 0, 0, 0);
        __builtin_amdgcn_s_setprio(0);
    };

    // ---- main loop ----
    LOAD(0);
    STORE(0);
    __syncthreads();
    for (int ts = 0; ts < 64; ++ts) {
        if (ts < 63) LOAD(ts + 1);        // globals fly under COMPUTE
        COMPUTE(ts & 1, kg);
        if (ts < 63) STORE((ts + 1) & 1); // waits loads, writes other buf
        __syncthreads();
    }

    // ---- LoRA rank-16 extra K-step into buf0 (k 0..15 data, 16..31 zeros) ----
    {
#pragma unroll
        for (int i = 0; i < 4; ++i) {
            int row = i * 32 + arow;
            union { p2 h[4]; iv4 v; } u;
            if (ag < 2) {
                const float* xp2 = xa + (size_t)(bm0 + row) * 16 + ag * 8;
                fv4 v0 = *(const fv4*)(xp2);
                fv4 v1 = *(const fv4*)(xp2 + 4);
                u.h[0] = __builtin_amdgcn_cvt_pkrtz(v0.x, v0.y);
                u.h[1] = __builtin_amdgcn_cvt_pkrtz(v0.z, v0.w);
                u.h[2] = __builtin_amdgcn_cvt_pkrtz(v1.x, v1.y);
                u.h[3] = __builtin_amdgcn_cvt_pkrtz(v1.z, v1.w);
            } else {
                u.v = iv4{0, 0, 0, 0};
            }
            *(iv4*)(lds + row * 128 + ((ag ^ (row & 7)) << 4)) = u.v;
        }
        float al = alphap[0];
        union { p2 h[4]; iv4 v; } ob0, ob1;
        if (q4 == 0) {
            const float* wp = lb + (size_t)(bn0 + colB) * 16;
#pragma unroll
            for (int e = 0; e < 4; ++e) {
                ob0.h[e] = __builtin_amdgcn_cvt_pkrtz(al * wp[2 * e], al * wp[2 * e + 1]);
                ob1.h[e] = __builtin_amdgcn_cvt_pkrtz(al * wp[8 + 2 * e], al * wp[9 + 2 * e]);
            }
        } else {
            ob0.v = iv4{0, 0, 0, 0};
            ob1.v = iv4{0, 0, 0, 0};
        }
        int c7 = colB & 7;
        *(iv4*)(lds + 32768 + colB * 128 + (((2 * q4) ^ c7) << 4)) = ob0.v;
        *(iv4*)(lds + 32768 + colB * 128 + (((2 * q4 + 1) ^ c7) << 4)) = ob1.v;
    }
    __syncthreads();

    if (kg == 0) {
        COMPUTE(0, 0);
    } else {
        // kg==1: dump partials for the kg==0 partner (same wm).
        char* dmp = lds + 49152 + wm * 16384;
#pragma unroll
        for (int m = 0; m < 4; ++m)
#pragma unroll
            for (int n = 0; n < 4; ++n)
                *(fv4*)(dmp + (m * 4 + n) * 1024 + lane * 16) = acc[m][n];
    }
    __syncthreads();

    if (kg == 0) {
        const char* dmp = lds + 49152 + wm * 16384;
#pragma unroll
        for (int m = 0; m < 4; ++m) {
            int row0 = bm0 + wm * 64 + m * 16 + hq * 4;
#pragma unroll
            for (int n = 0; n < 4; ++n) {
                fv4 p = *(const fv4*)(dmp + (m * 4 + n) * 1024 + lane * 16);
                fv4 v = acc[m][n];
                v.x += p.x; v.y += p.y; v.z += p.z; v.w += p.w;
                int col = bn0 + n * 16 + rl;
#pragma unroll
                for (int r = 0; r < 4; ++r)
                    out[(size_t)(row0 + r) * N_OUT + col] = v[r];
            }
        }
    }
}

extern "C" void kernel_launch(void* const* d_in, const int* in_sizes, int n_in,
                              void* d_out, int out_size, void* d_ws, size_t ws_size,
                              hipStream_t stream) {
    const float* x  = (const float*)d_in[0];
    const int*   qw = (const int*)d_in[1];
    const float* sc = (const float*)d_in[2];
    const float* la = (const float*)d_in[3];
    const float* lb = (const float*)d_in[4];
    const float* al = (const float*)d_in[5];
    float* out = (float*)d_out;
    float* xa  = (float*)d_ws;   // 1024*16 fp32 = 64 KB scratch

    xa_kernel<<<1024, 256, 0, stream>>>(x, la, xa);
    qlora_gemm<<<512, 256, 0, stream>>>(x, qw, sc, lb, al, xa, out);
}